// Round 2
// baseline (346.261 us; speedup 1.0000x reference)
//
#include <hip/hip_runtime.h>
#include <hip/hip_bf16.h>
#include <math.h>

#define N_NODES 50000
#define N_EDGES 800000
#define DIM 64
#define SCAN_NBLK 196   // ceil(50000/256)

typedef __bf16 bf16x8 __attribute__((ext_vector_type(8)));
typedef float f32x4 __attribute__((ext_vector_type(4)));

// ---------------------------------------------------------------------------
// K1: per-node transform. U[i] = (W1a - W1b) x_i + b1 ; V[j] = W1b x_j
// ---------------------------------------------------------------------------
__global__ __launch_bounds__(256) void node_uv_kernel(
    const float* __restrict__ x, const float* __restrict__ W1,
    const float* __restrict__ b1, float* __restrict__ U, float* __restrict__ V)
{
    const int lane  = threadIdx.x & 63;
    const int wave  = (int)((blockIdx.x * blockDim.x + threadIdx.x) >> 6);
    const int nwav  = (int)((gridDim.x * blockDim.x) >> 6);

    float wa[64], wb[64];
#pragma unroll
    for (int k4 = 0; k4 < 16; ++k4) {
        float4 pa = *(const float4*)(W1 + lane * 128 + k4 * 4);
        float4 pb = *(const float4*)(W1 + lane * 128 + 64 + k4 * 4);
        wa[k4 * 4 + 0] = pa.x - pb.x;  wb[k4 * 4 + 0] = pb.x;
        wa[k4 * 4 + 1] = pa.y - pb.y;  wb[k4 * 4 + 1] = pb.y;
        wa[k4 * 4 + 2] = pa.z - pb.z;  wb[k4 * 4 + 2] = pb.z;
        wa[k4 * 4 + 3] = pa.w - pb.w;  wb[k4 * 4 + 3] = pb.w;
    }
    const float bias = b1[lane];

    for (int i = wave; i < N_NODES; i += nwav) {
        float xv = x[i * 64 + lane];
        float u = bias, v = 0.f;
#pragma unroll
        for (int k = 0; k < 64; ++k) {
            float xk = __int_as_float(
                __builtin_amdgcn_readlane(__float_as_int(xv), k));
            u = fmaf(wa[k], xk, u);
            v = fmaf(wb[k], xk, v);
        }
        U[i * 64 + lane] = u;
        V[i * 64 + lane] = v;
    }
}

// ---------------------------------------------------------------------------
// K2: split W2 (fp32) into hi/lo bf16 pair for 3-MFMA near-fp32 matmul.
// ---------------------------------------------------------------------------
__global__ void w2split_kernel(const float* __restrict__ W2,
                               __bf16* __restrict__ hi, __bf16* __restrict__ lo)
{
    int i = blockIdx.x * blockDim.x + threadIdx.x;
    if (i < 64 * 64) {
        float w   = W2[i];
        __bf16 h  = (__bf16)w;
        hi[i] = h;
        lo[i] = (__bf16)(w - (float)h);
    }
}

// ---------------------------------------------------------------------------
// CSR build: histogram -> exclusive scan -> scatter (counting sort by dst)
// ---------------------------------------------------------------------------
__global__ void hist_kernel(const int* __restrict__ dst, int* __restrict__ counts)
{
    int e = blockIdx.x * blockDim.x + threadIdx.x;
    if (e < N_EDGES) atomicAdd(&counts[dst[e]], 1);
}

__global__ void scan_block_reduce(const int* __restrict__ counts,
                                  int* __restrict__ bsums)
{
    __shared__ int s[256];
    int i = blockIdx.x * 256 + threadIdx.x;
    s[threadIdx.x] = (i < N_NODES) ? counts[i] : 0;
    __syncthreads();
    for (int off = 128; off > 0; off >>= 1) {
        if (threadIdx.x < off) s[threadIdx.x] += s[threadIdx.x + off];
        __syncthreads();
    }
    if (threadIdx.x == 0) bsums[blockIdx.x] = s[0];
}

__global__ void scan_sums(int* __restrict__ bsums)
{
    __shared__ int s[256];
    int t = threadIdx.x;
    int v = (t < SCAN_NBLK) ? bsums[t] : 0;
    s[t] = v; __syncthreads();
    for (int off = 1; off < 256; off <<= 1) {
        int x = (t >= off) ? s[t - off] : 0;
        __syncthreads();
        s[t] += x;
        __syncthreads();
    }
    if (t < SCAN_NBLK) bsums[t] = s[t] - v;   // exclusive
}

__global__ void scan_block_final(const int* __restrict__ counts,
                                 const int* __restrict__ bsums,
                                 int* __restrict__ row_start,
                                 int* __restrict__ cursor)
{
    __shared__ int s[256];
    int i = blockIdx.x * 256 + threadIdx.x;
    int t = threadIdx.x;
    int v = (i < N_NODES) ? counts[i] : 0;
    s[t] = v; __syncthreads();
    for (int off = 1; off < 256; off <<= 1) {
        int x = (t >= off) ? s[t - off] : 0;
        __syncthreads();
        s[t] += x;
        __syncthreads();
    }
    int ex = s[t] - v + bsums[blockIdx.x];
    if (i < N_NODES) { row_start[i] = ex; cursor[i] = ex; }
    if (i == 0) row_start[N_NODES] = N_EDGES;
}

__global__ void scatter_kernel(const int* __restrict__ ei,
                               int* __restrict__ cursor,
                               int* __restrict__ sorted_src)
{
    int e = blockIdx.x * blockDim.x + threadIdx.x;
    if (e < N_EDGES) {
        int d = ei[N_EDGES + e];               // dst
        int pos = atomicAdd(&cursor[d], 1);
        sorted_src[pos] = ei[e];               // src
    }
}

// ---------------------------------------------------------------------------
// K8: one wave per node. max-reduce msgs over the node's CSR segment in
// registers, single coalesced 256B output write. No atomics.
//
// MFMA fragment layouts (HW-verified):
//   A: lane = m + 16q holds A[m][k], k = 32s + 8q + j  (j=0..7), m = edge slot
//   B: lane = n + 16q holds B[k][n] = W2[n][k], same k mapping
//   D: lane holds D[4q + r][lane&15], r=0..3   (row = edge slot, col = out dim)
// ---------------------------------------------------------------------------
__global__ __launch_bounds__(256) void node_gather_kernel(
    const int* __restrict__ row_start, const int* __restrict__ sorted_src,
    const float* __restrict__ U, const float* __restrict__ V,
    const __bf16* __restrict__ w2hi, const __bf16* __restrict__ w2lo,
    const float* __restrict__ b2, float* __restrict__ out)
{
    const int lane = threadIdx.x & 63;
    const int m    = lane & 15;
    const int q    = lane >> 4;
    const int node = (int)((blockIdx.x * blockDim.x + threadIdx.x) >> 6);
    if (node >= N_NODES) return;

    const int beg = row_start[node];
    const int len = row_start[node + 1] - beg;

    if (len == 0) { out[node * 64 + lane] = 0.f; return; }

    // B fragments (W2 hi/lo), n = t*16 + m
    bf16x8 bhi[4][2], blo[4][2];
#pragma unroll
    for (int t = 0; t < 4; ++t)
#pragma unroll
        for (int s = 0; s < 2; ++s) {
            bhi[t][s] = *(const bf16x8*)(w2hi + (t * 16 + m) * 64 + s * 32 + q * 8);
            blo[t][s] = *(const bf16x8*)(w2lo + (t * 16 + m) * 64 + s * 32 + q * 8);
        }

    // U[node] slice for this lane's k positions (identical across m — broadcast)
    float uf[16];
    {
        const float4* u0 = (const float4*)(U + node * 64 + q * 8);
        const float4* u1 = (const float4*)(U + node * 64 + 32 + q * 8);
        float4 a = u0[0], b = u0[1], c = u1[0], d = u1[1];
        uf[0]=a.x; uf[1]=a.y; uf[2]=a.z; uf[3]=a.w;
        uf[4]=b.x; uf[5]=b.y; uf[6]=b.z; uf[7]=b.w;
        uf[8]=c.x; uf[9]=c.y; uf[10]=c.z; uf[11]=c.w;
        uf[12]=d.x; uf[13]=d.y; uf[14]=d.z; uf[15]=d.w;
    }

    f32x4 mx[4];
#pragma unroll
    for (int t = 0; t < 4; ++t)
        mx[t] = f32x4{-INFINITY, -INFINITY, -INFINITY, -INFINITY};

    for (int base = 0; base < len; base += 16) {
        int el = base + m;
        if (el > len - 1) el = len - 1;          // pad by duplicating last edge
        const int si = sorted_src[beg + el];

        bf16x8 ahi[2], alo[2];
#pragma unroll
        for (int s = 0; s < 2; ++s) {
            const float4* vp = (const float4*)(V + si * 64 + s * 32 + q * 8);
            float4 v0 = vp[0], v1 = vp[1];
            float hv[8] = {uf[s*8+0]+v0.x, uf[s*8+1]+v0.y, uf[s*8+2]+v0.z, uf[s*8+3]+v0.w,
                           uf[s*8+4]+v1.x, uf[s*8+5]+v1.y, uf[s*8+6]+v1.z, uf[s*8+7]+v1.w};
#pragma unroll
            for (int j = 0; j < 8; ++j) {
                float h = hv[j];
                h = (h >= 0.f) ? h : 0.01f * h;          // LeakyReLU
                __bf16 hb = (__bf16)h;
                ahi[s][j] = hb;
                alo[s][j] = (__bf16)(h - (float)hb);     // residual
            }
        }

#pragma unroll
        for (int t = 0; t < 4; ++t) {
            f32x4 acc = {0.f, 0.f, 0.f, 0.f};
#pragma unroll
            for (int s = 0; s < 2; ++s) {
                acc = __builtin_amdgcn_mfma_f32_16x16x32_bf16(ahi[s], bhi[t][s], acc, 0, 0, 0);
                acc = __builtin_amdgcn_mfma_f32_16x16x32_bf16(alo[s], bhi[t][s], acc, 0, 0, 0);
                acc = __builtin_amdgcn_mfma_f32_16x16x32_bf16(ahi[s], blo[t][s], acc, 0, 0, 0);
            }
#pragma unroll
            for (int r = 0; r < 4; ++r) {
                int row = base + q * 4 + r;              // edge slot of this D reg
                if (row < len) mx[t][r] = fmaxf(mx[t][r], acc[r]);
            }
        }
    }

    // reduce over rows: in-lane (4 regs) then across q (lanes m, m+16, m+32, m+48)
    float red[4];
#pragma unroll
    for (int t = 0; t < 4; ++t) {
        float v = fmaxf(fmaxf(mx[t][0], mx[t][1]), fmaxf(mx[t][2], mx[t][3]));
        v = fmaxf(v, __shfl_xor(v, 16, 64));
        v = fmaxf(v, __shfl_xor(v, 32, 64));
        red[t] = v;
    }
    // lane = q*16 + m writes column n = lane: pick red[q]
    float outv = (q == 0) ? red[0] : (q == 1) ? red[1] : (q == 2) ? red[2] : red[3];
    out[node * 64 + lane] = tanhf(outv + b2[lane]);
}

// ---------------------------------------------------------------------------
extern "C" void kernel_launch(void* const* d_in, const int* in_sizes, int n_in,
                              void* d_out, int out_size, void* d_ws, size_t ws_size,
                              hipStream_t stream)
{
    const float* x  = (const float*)d_in[0];
    const int*   ei = (const int*)d_in[1];
    const float* W1 = (const float*)d_in[2];
    const float* b1 = (const float*)d_in[3];
    const float* W2 = (const float*)d_in[4];
    const float* b2 = (const float*)d_in[5];
    float* out = (float*)d_out;

    // workspace layout
    char* p = (char*)d_ws;
    float* U = (float*)p;                 p += (size_t)N_NODES * 64 * 4;
    float* V = (float*)p;                 p += (size_t)N_NODES * 64 * 4;
    __bf16* w2hi = (__bf16*)p;            p += 64 * 64 * 2;
    __bf16* w2lo = (__bf16*)p;            p += 64 * 64 * 2;
    int* counts     = (int*)p;            p += (size_t)N_NODES * 4;
    int* row_start  = (int*)p;            p += (size_t)(N_NODES + 1) * 4;
    int* cursor     = (int*)p;            p += (size_t)N_NODES * 4;
    int* bsums      = (int*)p;            p += 256 * 4;
    int* sorted_src = (int*)p;            p += (size_t)N_EDGES * 4;

    hipMemsetAsync(counts, 0, (size_t)N_NODES * 4, stream);
    w2split_kernel<<<16, 256, 0, stream>>>(W2, w2hi, w2lo);
    node_uv_kernel<<<1024, 256, 0, stream>>>(x, W1, b1, U, V);
    hist_kernel<<<(N_EDGES + 255) / 256, 256, 0, stream>>>(ei + N_EDGES, counts);
    scan_block_reduce<<<SCAN_NBLK, 256, 0, stream>>>(counts, bsums);
    scan_sums<<<1, 256, 0, stream>>>(bsums);
    scan_block_final<<<SCAN_NBLK, 256, 0, stream>>>(counts, bsums, row_start, cursor);
    scatter_kernel<<<(N_EDGES + 255) / 256, 256, 0, stream>>>(ei, cursor, sorted_src);
    node_gather_kernel<<<(N_NODES * 64 + 255) / 256, 256, 0, stream>>>(
        row_start, sorted_src, U, V, w2hi, w2lo, b2, out);
}

// Round 3
// 322.769 us; speedup vs baseline: 1.0728x; 1.0728x over previous
//
#include <hip/hip_runtime.h>
#include <hip/hip_bf16.h>
#include <math.h>

#define N_NODES 50000
#define N_EDGES 800000
#define DIM 64

typedef __bf16 bf16x8 __attribute__((ext_vector_type(8)));
typedef float f32x4 __attribute__((ext_vector_type(4)));

// Monotonic unsigned encoding of float: order-preserving, 0 < enc(any finite).
__device__ __forceinline__ unsigned enc_f32(float f) {
    unsigned b = __float_as_uint(f);
    return (b & 0x80000000u) ? ~b : (b | 0x80000000u);
}

// ---------------------------------------------------------------------------
// K1 (fused prep): block-range split into three jobs.
//   blocks [0,1024)    : U[i] = (W1a-W1b) x_i + b1 ; V[j] = W1b x_j  (wave/node)
//   blocks [1024,1152) : zero agg (= d_out) so 0u means "empty segment"
//   blocks [1152,1168) : split W2 into hi/lo bf16 for 3-MFMA near-fp32 matmul
// ---------------------------------------------------------------------------
#define UV_BLOCKS   1024
#define ZERO_BLOCKS 128
#define W2_BLOCKS   16
#define PREP_GRID   (UV_BLOCKS + ZERO_BLOCKS + W2_BLOCKS)

__global__ __launch_bounds__(256) void prep_kernel(
    const float* __restrict__ x, const float* __restrict__ W1,
    const float* __restrict__ b1, const float* __restrict__ W2,
    float* __restrict__ U, float* __restrict__ V,
    __bf16* __restrict__ w2hi, __bf16* __restrict__ w2lo,
    uint4* __restrict__ agg_zero)
{
    const int blk = blockIdx.x;
    if (blk < UV_BLOCKS) {
        const int lane = threadIdx.x & 63;
        const int wave = (int)((blk * 256 + threadIdx.x) >> 6);
        const int nwav = UV_BLOCKS * 4;

        float wa[64], wb[64];
#pragma unroll
        for (int k4 = 0; k4 < 16; ++k4) {
            float4 pa = *(const float4*)(W1 + lane * 128 + k4 * 4);
            float4 pb = *(const float4*)(W1 + lane * 128 + 64 + k4 * 4);
            wa[k4 * 4 + 0] = pa.x - pb.x;  wb[k4 * 4 + 0] = pb.x;
            wa[k4 * 4 + 1] = pa.y - pb.y;  wb[k4 * 4 + 1] = pb.y;
            wa[k4 * 4 + 2] = pa.z - pb.z;  wb[k4 * 4 + 2] = pb.z;
            wa[k4 * 4 + 3] = pa.w - pb.w;  wb[k4 * 4 + 3] = pb.w;
        }
        const float bias = b1[lane];

        for (int i = wave; i < N_NODES; i += nwav) {
            float xv = x[i * 64 + lane];
            float u = bias, v = 0.f;
#pragma unroll
            for (int k = 0; k < 64; ++k) {
                float xk = __int_as_float(
                    __builtin_amdgcn_readlane(__float_as_int(xv), k));
                u = fmaf(wa[k], xk, u);
                v = fmaf(wb[k], xk, v);
            }
            U[i * 64 + lane] = u;
            V[i * 64 + lane] = v;
        }
    } else if (blk < UV_BLOCKS + ZERO_BLOCKS) {
        // zero 50000*64 f32 = 800000 uint4
        const int tid = (blk - UV_BLOCKS) * 256 + threadIdx.x;   // 32768 threads
        const uint4 z = {0u, 0u, 0u, 0u};
        for (int i = tid; i < (N_NODES * 64 / 4); i += ZERO_BLOCKS * 256)
            agg_zero[i] = z;
    } else {
        const int i = (blk - UV_BLOCKS - ZERO_BLOCKS) * 256 + threadIdx.x;
        if (i < 64 * 64) {
            float w  = W2[i];
            __bf16 h = (__bf16)w;
            w2hi[i] = h;
            w2lo[i] = (__bf16)(w - (float)h);
        }
    }
}

// ---------------------------------------------------------------------------
// K2: per-edge MLP + check-then-atomic scatter-max.
// One wave per 16-edge tile. h = leaky(U[dst]+V[src]) in fp32, split into
// hi/lo bf16 A-fragments; msg = h @ W2^T via 3x mfma_f32_16x16x32_bf16 per
// (n-tile, k-step). Scatter-max: plain load first, atomicMax only if the
// candidate wins (stale reads are safe — they can only cause EXTRA atomics,
// never skipped winners). Cuts atomic count ~51.2M -> ~14M (H_16 + races).
//
// MFMA fragment layouts (HW-verified, guide §3):
//   A: lane = m + 16q holds A[m][k], k = 32s + 8q + j  (j=0..7)
//   B: lane = n + 16q holds B[k][n] = W2[n][k], same k mapping
//   D: lane holds D[4q + r][lane&15], r=0..3  (row = edge slot in tile)
// ---------------------------------------------------------------------------
__global__ __launch_bounds__(256) void edge_kernel(
    const int* __restrict__ ei, const float* __restrict__ U,
    const float* __restrict__ V, const __bf16* __restrict__ w2hi,
    const __bf16* __restrict__ w2lo, const float* __restrict__ b2,
    unsigned* __restrict__ agg)
{
    const int lane = threadIdx.x & 63;
    const int m    = lane & 15;
    const int q    = lane >> 4;
    const int wave = (int)((blockIdx.x * blockDim.x + threadIdx.x) >> 6);
    const int nwav = (int)((gridDim.x * blockDim.x) >> 6);

    const int* __restrict__ srcp = ei;             // edge_index[0]
    const int* __restrict__ dstp = ei + N_EDGES;   // edge_index[1]

    // Preload B fragments (W2 hi/lo) and bias. n = 16t + m.
    bf16x8 bhi[4][2], blo[4][2];
    float bias[4];
#pragma unroll
    for (int t = 0; t < 4; ++t) {
        const int n = t * 16 + m;
#pragma unroll
        for (int s = 0; s < 2; ++s) {
            bhi[t][s] = *(const bf16x8*)(w2hi + n * 64 + s * 32 + q * 8);
            blo[t][s] = *(const bf16x8*)(w2lo + n * 64 + s * 32 + q * 8);
        }
        bias[t] = b2[n];
    }

    const int NT = N_EDGES / 16;
    for (int tile = wave; tile < NT; tile += nwav) {
        const int e  = tile * 16 + m;
        const int di = dstp[e];
        const int si = srcp[e];
        // dst indices for the D-layout rows this lane will write (edges 4q+r)
        const int4 d4 = *(const int4*)(dstp + tile * 16 + q * 4);
        const int drow[4] = {d4.x, d4.y, d4.z, d4.w};

        bf16x8 ahi[2], alo[2];
#pragma unroll
        for (int s = 0; s < 2; ++s) {
            const float4* up = (const float4*)(U + di * 64 + s * 32 + q * 8);
            const float4* vp = (const float4*)(V + si * 64 + s * 32 + q * 8);
            float4 u0 = up[0], u1 = up[1];
            float4 v0 = vp[0], v1 = vp[1];
            float hv[8] = {u0.x + v0.x, u0.y + v0.y, u0.z + v0.z, u0.w + v0.w,
                           u1.x + v1.x, u1.y + v1.y, u1.z + v1.z, u1.w + v1.w};
#pragma unroll
            for (int j = 0; j < 8; ++j) {
                float h = hv[j];
                h = (h >= 0.f) ? h : 0.01f * h;         // LeakyReLU
                __bf16 hb = (__bf16)h;
                ahi[s][j] = hb;
                alo[s][j] = (__bf16)(h - (float)hb);    // residual
            }
        }

#pragma unroll
        for (int t = 0; t < 4; ++t) {
            f32x4 acc = {bias[t], bias[t], bias[t], bias[t]};
#pragma unroll
            for (int s = 0; s < 2; ++s) {
                acc = __builtin_amdgcn_mfma_f32_16x16x32_bf16(ahi[s], bhi[t][s], acc, 0, 0, 0);
                acc = __builtin_amdgcn_mfma_f32_16x16x32_bf16(alo[s], bhi[t][s], acc, 0, 0, 0);
                acc = __builtin_amdgcn_mfma_f32_16x16x32_bf16(ahi[s], blo[t][s], acc, 0, 0, 0);
            }
#pragma unroll
            for (int r = 0; r < 4; ++r) {
                const unsigned key = enc_f32(acc[r]);
                unsigned* addr = agg + (size_t)drow[r] * 64 + t * 16 + m;
                if (*addr < key) atomicMax(addr, key);   // check-then-atomic
            }
        }
    }
}

// ---------------------------------------------------------------------------
// K3: decode encoded max in place, empty-segment fill 0, tanh.
// ---------------------------------------------------------------------------
__global__ __launch_bounds__(256) void finalize_kernel(unsigned* __restrict__ data)
{
    const int stride = gridDim.x * blockDim.x;
    for (int i = blockIdx.x * blockDim.x + threadIdx.x; i < N_NODES * 64; i += stride) {
        unsigned key = data[i];
        float out = 0.f;
        if (key != 0u) {
            unsigned b = (key & 0x80000000u) ? (key & 0x7FFFFFFFu) : ~key;
            out = tanhf(__uint_as_float(b));
        }
        ((float*)data)[i] = out;
    }
}

// ---------------------------------------------------------------------------
extern "C" void kernel_launch(void* const* d_in, const int* in_sizes, int n_in,
                              void* d_out, int out_size, void* d_ws, size_t ws_size,
                              hipStream_t stream)
{
    const float* x  = (const float*)d_in[0];
    const int*   ei = (const int*)d_in[1];
    const float* W1 = (const float*)d_in[2];
    const float* b1 = (const float*)d_in[3];
    const float* W2 = (const float*)d_in[4];
    const float* b2 = (const float*)d_in[5];

    char* p = (char*)d_ws;
    float* U = (float*)p;                 p += (size_t)N_NODES * 64 * 4;
    float* V = (float*)p;                 p += (size_t)N_NODES * 64 * 4;
    __bf16* w2hi = (__bf16*)p;            p += 64 * 64 * 2;
    __bf16* w2lo = (__bf16*)p;            p += 64 * 64 * 2;
    unsigned* agg = (unsigned*)d_out;     // reuse d_out as aggregation buffer

    prep_kernel<<<PREP_GRID, 256, 0, stream>>>(x, W1, b1, W2, U, V, w2hi, w2lo,
                                               (uint4*)agg);
    edge_kernel<<<2048, 256, 0, stream>>>(ei, U, V, w2hi, w2lo, b2, agg);
    finalize_kernel<<<1024, 256, 0, stream>>>(agg);
}

// Round 4
// 293.236 us; speedup vs baseline: 1.1808x; 1.1007x over previous
//
#include <hip/hip_runtime.h>
#include <hip/hip_bf16.h>
#include <math.h>

#define N_NODES 50000
#define N_EDGES 800000
#define MAX_TILES 100032   // sum ceil(deg/16) <= (800000 + 50000*15)/16 = 96875

typedef __bf16 bf16x8 __attribute__((ext_vector_type(8)));
typedef float f32x4 __attribute__((ext_vector_type(4)));

// Monotonic unsigned encoding of float: order-preserving, 0 < enc(any finite).
__device__ __forceinline__ unsigned enc_f32(float f) {
    unsigned b = __float_as_uint(f);
    return (b & 0x80000000u) ? ~b : (b | 0x80000000u);
}

// ---------------------------------------------------------------------------
// K1 (fused prep), block-range split:
//   [0,1024)    : U[i] = (W1a-W1b) x_i + b1 ; V[j] = W1b x_j   (wave per node)
//   [1024,1152) : zero agg (12.8MB), counts (200KB), counters
//   [1152,1168) : split W2 into hi/lo bf16 (3-MFMA near-fp32 scheme)
// ---------------------------------------------------------------------------
#define UV_BLOCKS   1024
#define ZERO_BLOCKS 128
#define W2_BLOCKS   16
#define PREP_GRID   (UV_BLOCKS + ZERO_BLOCKS + W2_BLOCKS)

__global__ __launch_bounds__(256) void prep_kernel(
    const float* __restrict__ x, const float* __restrict__ W1,
    const float* __restrict__ b1, const float* __restrict__ W2,
    float* __restrict__ U, float* __restrict__ V,
    __bf16* __restrict__ w2hi, __bf16* __restrict__ w2lo,
    uint4* __restrict__ agg_zero, int* __restrict__ counts,
    int* __restrict__ counters)
{
    const int blk = blockIdx.x;
    if (blk < UV_BLOCKS) {
        const int lane = threadIdx.x & 63;
        const int wave = (int)((blk * 256 + threadIdx.x) >> 6);
        const int nwav = UV_BLOCKS * 4;

        float wa[64], wb[64];
#pragma unroll
        for (int k4 = 0; k4 < 16; ++k4) {
            float4 pa = *(const float4*)(W1 + lane * 128 + k4 * 4);
            float4 pb = *(const float4*)(W1 + lane * 128 + 64 + k4 * 4);
            wa[k4 * 4 + 0] = pa.x - pb.x;  wb[k4 * 4 + 0] = pb.x;
            wa[k4 * 4 + 1] = pa.y - pb.y;  wb[k4 * 4 + 1] = pb.y;
            wa[k4 * 4 + 2] = pa.z - pb.z;  wb[k4 * 4 + 2] = pb.z;
            wa[k4 * 4 + 3] = pa.w - pb.w;  wb[k4 * 4 + 3] = pb.w;
        }
        const float bias = b1[lane];

        for (int i = wave; i < N_NODES; i += nwav) {
            float xv = x[i * 64 + lane];
            float u = bias, v = 0.f;
#pragma unroll
            for (int k = 0; k < 64; ++k) {
                float xk = __int_as_float(
                    __builtin_amdgcn_readlane(__float_as_int(xv), k));
                u = fmaf(wa[k], xk, u);
                v = fmaf(wb[k], xk, v);
            }
            U[i * 64 + lane] = u;
            V[i * 64 + lane] = v;
        }
    } else if (blk < UV_BLOCKS + ZERO_BLOCKS) {
        const int tid = (blk - UV_BLOCKS) * 256 + threadIdx.x;   // 32768 threads
        const uint4 z = {0u, 0u, 0u, 0u};
        for (int i = tid; i < (N_NODES * 64 / 4); i += ZERO_BLOCKS * 256)
            agg_zero[i] = z;
        for (int i = tid; i < N_NODES; i += ZERO_BLOCKS * 256)
            counts[i] = 0;
        if (tid < 2) counters[tid] = 0;
    } else {
        const int i = (blk - UV_BLOCKS - ZERO_BLOCKS) * 256 + threadIdx.x;
        if (i < 64 * 64) {
            float w  = W2[i];
            __bf16 h = (__bf16)w;
            w2hi[i] = h;
            w2lo[i] = (__bf16)(w - (float)h);
        }
    }
}

// ---------------------------------------------------------------------------
// K2: degree histogram over dst.
// ---------------------------------------------------------------------------
__global__ __launch_bounds__(256) void hist_kernel(const int* __restrict__ dst,
                                                   int* __restrict__ counts)
{
    int e = blockIdx.x * blockDim.x + threadIdx.x;
    if (e < N_EDGES) atomicAdd(&counts[dst[e]], 1);
}

// ---------------------------------------------------------------------------
// K3: allocate contiguous edge segment + emit node-aligned 16-edge tiles.
// Segment order across nodes is nondeterministic (atomic alloc) — harmless,
// max-aggregation is order-free. counters[0]=edge cursor, counters[1]=tiles.
// ---------------------------------------------------------------------------
__global__ __launch_bounds__(256) void alloc_kernel(
    const int* __restrict__ counts, int* __restrict__ cursor,
    int4* __restrict__ tiles, int* __restrict__ counters)
{
    int i = blockIdx.x * blockDim.x + threadIdx.x;
    if (i >= N_NODES) return;
    int deg = counts[i];
    if (deg == 0) return;
    int nt    = (deg + 15) >> 4;
    int ebase = atomicAdd(&counters[0], deg);
    int tbase = atomicAdd(&counters[1], nt);
    cursor[i] = ebase;
    for (int j = 0; j < nt; ++j) {
        int beg = ebase + j * 16;
        int cnt = deg - j * 16; if (cnt > 16) cnt = 16;
        tiles[tbase + j] = make_int4(i, beg, cnt, 0);
    }
}

// ---------------------------------------------------------------------------
// K4: scatter src ids into dst-grouped segments.
// ---------------------------------------------------------------------------
__global__ __launch_bounds__(256) void scatter_kernel(
    const int* __restrict__ ei, int* __restrict__ cursor,
    int* __restrict__ ssrc)
{
    int e = blockIdx.x * blockDim.x + threadIdx.x;
    if (e < N_EDGES) {
        int d = ei[N_EDGES + e];
        int pos = atomicAdd(&cursor[d], 1);
        ssrc[pos] = ei[e];
    }
}

// ---------------------------------------------------------------------------
// K5: per-tile MLP + in-register/shfl max reduce + 64 atomics per tile.
// Tile = up to 16 edges of ONE node (short tiles pad by duplicating the last
// edge — duplicates are harmless under max). h = leaky(U[node]+V[src]) in
// fp32, hi/lo bf16 split; msg = h @ W2^T via 3x mfma_f32_16x16x32_bf16 per
// (t, s). No bias in acc (b2 folded into finalize: max(m+b2)=max(m)+b2).
//
// MFMA layouts (HW-verified):
//   A: lane m+16q holds A[m][k], k = 32s+8q+j  (m = edge slot)
//   B: lane n+16q holds B[k][n] = W2[n][k]
//   D: lane holds D[4q+r][lane&15] -> in-lane max over r, shfl over q.
// ---------------------------------------------------------------------------
__global__ __launch_bounds__(256) void edge_tile_kernel(
    const int4* __restrict__ tiles, const int* __restrict__ counters,
    const int* __restrict__ ssrc, const float* __restrict__ U,
    const float* __restrict__ V, const __bf16* __restrict__ w2hi,
    const __bf16* __restrict__ w2lo, unsigned* __restrict__ agg)
{
    const int lane = threadIdx.x & 63;
    const int m    = lane & 15;
    const int q    = lane >> 4;
    const int wave = (int)((blockIdx.x * blockDim.x + threadIdx.x) >> 6);
    const int nwav = (int)((gridDim.x * blockDim.x) >> 6);
    const int ntiles = counters[1];

    bf16x8 bhi[4][2], blo[4][2];
#pragma unroll
    for (int t = 0; t < 4; ++t)
#pragma unroll
        for (int s = 0; s < 2; ++s) {
            bhi[t][s] = *(const bf16x8*)(w2hi + (t * 16 + m) * 64 + s * 32 + q * 8);
            blo[t][s] = *(const bf16x8*)(w2lo + (t * 16 + m) * 64 + s * 32 + q * 8);
        }

    for (int tt = wave; tt < ntiles; tt += nwav) {
        const int4 rec = tiles[tt];
        const int node = rec.x, beg = rec.y, cnt = rec.z;

        int el = (m < cnt) ? m : cnt - 1;
        const int si = ssrc[beg + el];

        // U[node] broadcast slice for this lane's k positions
        float uf[16];
        {
            const float4* u0 = (const float4*)(U + node * 64 + q * 8);
            const float4* u1 = (const float4*)(U + node * 64 + 32 + q * 8);
            float4 a = u0[0], b = u0[1], c = u1[0], d = u1[1];
            uf[0]=a.x; uf[1]=a.y; uf[2]=a.z; uf[3]=a.w;
            uf[4]=b.x; uf[5]=b.y; uf[6]=b.z; uf[7]=b.w;
            uf[8]=c.x; uf[9]=c.y; uf[10]=c.z; uf[11]=c.w;
            uf[12]=d.x; uf[13]=d.y; uf[14]=d.z; uf[15]=d.w;
        }

        bf16x8 ahi[2], alo[2];
#pragma unroll
        for (int s = 0; s < 2; ++s) {
            const float4* vp = (const float4*)(V + si * 64 + s * 32 + q * 8);
            float4 v0 = vp[0], v1 = vp[1];
            float hv[8] = {uf[s*8+0]+v0.x, uf[s*8+1]+v0.y, uf[s*8+2]+v0.z, uf[s*8+3]+v0.w,
                           uf[s*8+4]+v1.x, uf[s*8+5]+v1.y, uf[s*8+6]+v1.z, uf[s*8+7]+v1.w};
#pragma unroll
            for (int j = 0; j < 8; ++j) {
                float h = hv[j];
                h = (h >= 0.f) ? h : 0.01f * h;          // LeakyReLU
                __bf16 hb = (__bf16)h;
                ahi[s][j] = hb;
                alo[s][j] = (__bf16)(h - (float)hb);     // residual
            }
        }

        float red[4];
#pragma unroll
        for (int t = 0; t < 4; ++t) {
            f32x4 acc = {0.f, 0.f, 0.f, 0.f};
#pragma unroll
            for (int s = 0; s < 2; ++s) {
                acc = __builtin_amdgcn_mfma_f32_16x16x32_bf16(ahi[s], bhi[t][s], acc, 0, 0, 0);
                acc = __builtin_amdgcn_mfma_f32_16x16x32_bf16(alo[s], bhi[t][s], acc, 0, 0, 0);
                acc = __builtin_amdgcn_mfma_f32_16x16x32_bf16(ahi[s], blo[t][s], acc, 0, 0, 0);
            }
            float v = fmaxf(fmaxf(acc[0], acc[1]), fmaxf(acc[2], acc[3]));
            v = fmaxf(v, __shfl_xor(v, 16, 64));
            v = fmaxf(v, __shfl_xor(v, 32, 64));
            red[t] = v;   // max over all 16 rows, col = t*16+m, uniform in q
        }
        float outv = (q == 0) ? red[0] : (q == 1) ? red[1]
                   : (q == 2) ? red[2] : red[3];          // col == lane
        atomicMax(agg + (size_t)node * 64 + lane, enc_f32(outv));
    }
}

// ---------------------------------------------------------------------------
// K6: decode max, add b2, tanh; empty segment (never written) -> 0.
// ---------------------------------------------------------------------------
__global__ __launch_bounds__(256) void finalize_kernel(
    unsigned* __restrict__ data, const float* __restrict__ b2)
{
    const int stride = gridDim.x * blockDim.x;
    for (int i = blockIdx.x * blockDim.x + threadIdx.x; i < N_NODES * 64; i += stride) {
        unsigned key = data[i];
        float out = 0.f;
        if (key != 0u) {
            unsigned b = (key & 0x80000000u) ? (key & 0x7FFFFFFFu) : ~key;
            out = tanhf(__uint_as_float(b) + b2[i & 63]);
        }
        ((float*)data)[i] = out;
    }
}

// ---------------------------------------------------------------------------
extern "C" void kernel_launch(void* const* d_in, const int* in_sizes, int n_in,
                              void* d_out, int out_size, void* d_ws, size_t ws_size,
                              hipStream_t stream)
{
    const float* x  = (const float*)d_in[0];
    const int*   ei = (const int*)d_in[1];
    const float* W1 = (const float*)d_in[2];
    const float* b1 = (const float*)d_in[3];
    const float* W2 = (const float*)d_in[4];
    const float* b2 = (const float*)d_in[5];

    char* p = (char*)d_ws;
    float* U = (float*)p;                  p += (size_t)N_NODES * 64 * 4;
    float* V = (float*)p;                  p += (size_t)N_NODES * 64 * 4;
    __bf16* w2hi = (__bf16*)p;             p += 64 * 64 * 2;
    __bf16* w2lo = (__bf16*)p;             p += 64 * 64 * 2;
    int* counts   = (int*)p;               p += (size_t)N_NODES * 4;
    int* cursor   = (int*)p;               p += (size_t)N_NODES * 4;
    int* counters = (int*)p;               p += 16;
    int4* tiles   = (int4*)p;              p += (size_t)MAX_TILES * 16;
    int* ssrc     = (int*)p;               p += (size_t)N_EDGES * 4;
    unsigned* agg = (unsigned*)d_out;      // reuse d_out as aggregation buffer

    prep_kernel<<<PREP_GRID, 256, 0, stream>>>(x, W1, b1, W2, U, V, w2hi, w2lo,
                                               (uint4*)agg, counts, counters);
    hist_kernel<<<(N_EDGES + 255) / 256, 256, 0, stream>>>(ei + N_EDGES, counts);
    alloc_kernel<<<(N_NODES + 255) / 256, 256, 0, stream>>>(counts, cursor,
                                                            tiles, counters);
    scatter_kernel<<<(N_EDGES + 255) / 256, 256, 0, stream>>>(ei, cursor, ssrc);
    edge_tile_kernel<<<2048, 256, 0, stream>>>(tiles, counters, ssrc, U, V,
                                               w2hi, w2lo, agg);
    finalize_kernel<<<512, 256, 0, stream>>>(agg, b2);
}

// Round 5
// 230.444 us; speedup vs baseline: 1.5026x; 1.2725x over previous
//
#include <hip/hip_runtime.h>
#include <hip/hip_bf16.h>
#include <math.h>

#define N_NODES 50000
#define N_EDGES 800000
#define CAP 48          // bucket capacity; Poisson(16) max-degree ~40 on this data
#define MAX_OVF 4096    // overflow list (exact-correctness fallback, ~always empty)

typedef __bf16 bf16x8 __attribute__((ext_vector_type(8)));
typedef float f32x4 __attribute__((ext_vector_type(4)));

// ---------------------------------------------------------------------------
// K1 (fused prep), block-range split:
//   [0,1024)    : U[i] = (W1a-W1b) x_i + b1 ; V[j] = W1b x_j   (wave per node)
//   [1024,1056) : zero counts + overflow counter
//   [1056,1072) : split W2 into hi/lo bf16 (3-MFMA near-fp32 scheme)
// ---------------------------------------------------------------------------
#define UV_BLOCKS 1024
#define Z_BLOCKS  32
#define W2_BLOCKS 16
#define PREP_GRID (UV_BLOCKS + Z_BLOCKS + W2_BLOCKS)

__global__ __launch_bounds__(256) void prep_kernel(
    const float* __restrict__ x, const float* __restrict__ W1,
    const float* __restrict__ b1, const float* __restrict__ W2,
    float* __restrict__ U, float* __restrict__ V,
    __bf16* __restrict__ w2hi, __bf16* __restrict__ w2lo,
    int* __restrict__ counts, int* __restrict__ ovf_cnt)
{
    const int blk = blockIdx.x;
    if (blk < UV_BLOCKS) {
        const int lane = threadIdx.x & 63;
        const int wave = (int)((blk * 256 + threadIdx.x) >> 6);
        const int nwav = UV_BLOCKS * 4;

        float wa[64], wb[64];
#pragma unroll
        for (int k4 = 0; k4 < 16; ++k4) {
            float4 pa = *(const float4*)(W1 + lane * 128 + k4 * 4);
            float4 pb = *(const float4*)(W1 + lane * 128 + 64 + k4 * 4);
            wa[k4 * 4 + 0] = pa.x - pb.x;  wb[k4 * 4 + 0] = pb.x;
            wa[k4 * 4 + 1] = pa.y - pb.y;  wb[k4 * 4 + 1] = pb.y;
            wa[k4 * 4 + 2] = pa.z - pb.z;  wb[k4 * 4 + 2] = pb.z;
            wa[k4 * 4 + 3] = pa.w - pb.w;  wb[k4 * 4 + 3] = pb.w;
        }
        const float bias = b1[lane];

        for (int i = wave; i < N_NODES; i += nwav) {
            float xv = x[i * 64 + lane];
            float u = bias, v = 0.f;
#pragma unroll
            for (int k = 0; k < 64; ++k) {
                float xk = __int_as_float(
                    __builtin_amdgcn_readlane(__float_as_int(xv), k));
                u = fmaf(wa[k], xk, u);
                v = fmaf(wb[k], xk, v);
            }
            U[i * 64 + lane] = u;
            V[i * 64 + lane] = v;
        }
    } else if (blk < UV_BLOCKS + Z_BLOCKS) {
        const int tid = (blk - UV_BLOCKS) * 256 + threadIdx.x;   // 8192 threads
        for (int i = tid; i < N_NODES; i += Z_BLOCKS * 256) counts[i] = 0;
        if (tid == 0) *ovf_cnt = 0;
    } else {
        const int i = (blk - UV_BLOCKS - Z_BLOCKS) * 256 + threadIdx.x;
        if (i < 64 * 64) {
            float w  = W2[i];
            __bf16 h = (__bf16)w;
            w2hi[i] = h;
            w2lo[i] = (__bf16)(w - (float)h);
        }
    }
}

// ---------------------------------------------------------------------------
// K2: bucket scatter — counting + placement in one pass.
// counts[d] ends at the true degree; entries past CAP go to the overflow list.
// ---------------------------------------------------------------------------
__global__ __launch_bounds__(256) void scatter_kernel(
    const int* __restrict__ ei, int* __restrict__ counts,
    int* __restrict__ buckets, int2* __restrict__ ovf, int* __restrict__ ovf_cnt)
{
    int e = blockIdx.x * blockDim.x + threadIdx.x;
    if (e >= N_EDGES) return;
    const int s = ei[e];
    const int d = ei[N_EDGES + e];
    int pos = atomicAdd(&counts[d], 1);
    if (pos < CAP) {
        buckets[d * CAP + pos] = s;
    } else {
        int o = atomicAdd(ovf_cnt, 1);
        if (o < MAX_OVF) ovf[o] = make_int2(d, s);
    }
}

// ---------------------------------------------------------------------------
// K3: wave per node. ceil(deg/16) tiles of up to 16 edges; short tiles pad by
// duplicating the last edge (harmless under max). h = leaky(U[node]+V[src])
// in fp32, hi/lo bf16 split; msg = h @ W2^T via 3x mfma_f32_16x16x32_bf16 per
// (t,s). Running max over tiles in 4 scalars; ONE plain coalesced store of
// tanh(max + b2). b2 folded post-max (max(m+b2) = max(m)+b2). No atomics.
//
// MFMA layouts (HW-verified):
//   A: lane m+16q holds A[m][k], k = 32s+8q+j  (m = edge slot)
//   B: lane n+16q holds B[k][n] = W2[n][k]
//   D: lane holds D[4q+r][lane&15] -> in-lane max over r, shfl over q=16,32.
// ---------------------------------------------------------------------------
__global__ __launch_bounds__(256) void node_kernel(
    const int* __restrict__ counts, const int* __restrict__ buckets,
    const int2* __restrict__ ovf, const int* __restrict__ ovf_cnt,
    const float* __restrict__ U, const float* __restrict__ V,
    const __bf16* __restrict__ w2hi, const __bf16* __restrict__ w2lo,
    const float* __restrict__ b2, float* __restrict__ out)
{
    const int lane = threadIdx.x & 63;
    const int m    = lane & 15;
    const int q    = lane >> 4;
    const int wave = (int)((blockIdx.x * blockDim.x + threadIdx.x) >> 6);
    const int nwav = (int)((gridDim.x * blockDim.x) >> 6);

    bf16x8 bhi[4][2], blo[4][2];
#pragma unroll
    for (int t = 0; t < 4; ++t)
#pragma unroll
        for (int s = 0; s < 2; ++s) {
            bhi[t][s] = *(const bf16x8*)(w2hi + (t * 16 + m) * 64 + s * 32 + q * 8);
            blo[t][s] = *(const bf16x8*)(w2lo + (t * 16 + m) * 64 + s * 32 + q * 8);
        }
    const float b2v = b2[lane];

    for (int node = wave; node < N_NODES; node += nwav) {
        const int cnt = counts[node];
        if (cnt == 0) { out[node * 64 + lane] = 0.f; continue; }
        const int deg = (cnt < CAP) ? cnt : CAP;

        // U[node] broadcast slice for this lane's k positions (hoisted)
        float uf[16];
        {
            const float4* u0 = (const float4*)(U + node * 64 + q * 8);
            const float4* u1 = (const float4*)(U + node * 64 + 32 + q * 8);
            float4 a = u0[0], b = u0[1], c = u1[0], d = u1[1];
            uf[0]=a.x; uf[1]=a.y; uf[2]=a.z; uf[3]=a.w;
            uf[4]=b.x; uf[5]=b.y; uf[6]=b.z; uf[7]=b.w;
            uf[8]=c.x; uf[9]=c.y; uf[10]=c.z; uf[11]=c.w;
            uf[12]=d.x; uf[13]=d.y; uf[14]=d.z; uf[15]=d.w;
        }

        float runmax[4] = {-INFINITY, -INFINITY, -INFINITY, -INFINITY};

        for (int base = 0; base < deg; base += 16) {
            int el = base + m;
            if (el > deg - 1) el = deg - 1;            // duplicate-pad short tile
            const int si = buckets[node * CAP + el];

            bf16x8 ahi[2], alo[2];
#pragma unroll
            for (int s = 0; s < 2; ++s) {
                const float4* vp = (const float4*)(V + si * 64 + s * 32 + q * 8);
                float4 v0 = vp[0], v1 = vp[1];
                float hv[8] = {uf[s*8+0]+v0.x, uf[s*8+1]+v0.y, uf[s*8+2]+v0.z, uf[s*8+3]+v0.w,
                               uf[s*8+4]+v1.x, uf[s*8+5]+v1.y, uf[s*8+6]+v1.z, uf[s*8+7]+v1.w};
#pragma unroll
                for (int j = 0; j < 8; ++j) {
                    float h = hv[j];
                    h = (h >= 0.f) ? h : 0.01f * h;    // LeakyReLU
                    __bf16 hb = (__bf16)h;
                    ahi[s][j] = hb;
                    alo[s][j] = (__bf16)(h - (float)hb);
                }
            }

#pragma unroll
            for (int t = 0; t < 4; ++t) {
                f32x4 acc = {0.f, 0.f, 0.f, 0.f};
#pragma unroll
                for (int s = 0; s < 2; ++s) {
                    acc = __builtin_amdgcn_mfma_f32_16x16x32_bf16(ahi[s], bhi[t][s], acc, 0, 0, 0);
                    acc = __builtin_amdgcn_mfma_f32_16x16x32_bf16(alo[s], bhi[t][s], acc, 0, 0, 0);
                    acc = __builtin_amdgcn_mfma_f32_16x16x32_bf16(ahi[s], blo[t][s], acc, 0, 0, 0);
                }
                float v = fmaxf(fmaxf(acc[0], acc[1]), fmaxf(acc[2], acc[3]));
                v = fmaxf(v, __shfl_xor(v, 16, 64));
                v = fmaxf(v, __shfl_xor(v, 32, 64));
                runmax[t] = fmaxf(runmax[t], v);
            }
        }

        // exact-correctness fallback: degree exceeded CAP -> scan overflow list
        if (cnt > CAP) {
            int no = *ovf_cnt; if (no > MAX_OVF) no = MAX_OVF;
            for (int o = 0; o < no; ++o) {
                const int2 ds = ovf[o];
                if (ds.x != node) continue;
                const int si = ds.y;
                bf16x8 ahi[2], alo[2];
#pragma unroll
                for (int s = 0; s < 2; ++s) {
                    const float4* vp = (const float4*)(V + si * 64 + s * 32 + q * 8);
                    float4 v0 = vp[0], v1 = vp[1];
                    float hv[8] = {uf[s*8+0]+v0.x, uf[s*8+1]+v0.y, uf[s*8+2]+v0.z, uf[s*8+3]+v0.w,
                                   uf[s*8+4]+v1.x, uf[s*8+5]+v1.y, uf[s*8+6]+v1.z, uf[s*8+7]+v1.w};
#pragma unroll
                    for (int j = 0; j < 8; ++j) {
                        float h = hv[j];
                        h = (h >= 0.f) ? h : 0.01f * h;
                        __bf16 hb = (__bf16)h;
                        ahi[s][j] = hb;
                        alo[s][j] = (__bf16)(h - (float)hb);
                    }
                }
#pragma unroll
                for (int t = 0; t < 4; ++t) {
                    f32x4 acc = {0.f, 0.f, 0.f, 0.f};
#pragma unroll
                    for (int s = 0; s < 2; ++s) {
                        acc = __builtin_amdgcn_mfma_f32_16x16x32_bf16(ahi[s], bhi[t][s], acc, 0, 0, 0);
                        acc = __builtin_amdgcn_mfma_f32_16x16x32_bf16(alo[s], bhi[t][s], acc, 0, 0, 0);
                        acc = __builtin_amdgcn_mfma_f32_16x16x32_bf16(ahi[s], blo[t][s], acc, 0, 0, 0);
                    }
                    float v = fmaxf(fmaxf(acc[0], acc[1]), fmaxf(acc[2], acc[3]));
                    v = fmaxf(v, __shfl_xor(v, 16, 64));
                    v = fmaxf(v, __shfl_xor(v, 32, 64));
                    runmax[t] = fmaxf(runmax[t], v);
                }
            }
        }

        const float outv = (q == 0) ? runmax[0] : (q == 1) ? runmax[1]
                         : (q == 2) ? runmax[2] : runmax[3];   // col == lane
        out[node * 64 + lane] = tanhf(outv + b2v);
    }
}

// ---------------------------------------------------------------------------
extern "C" void kernel_launch(void* const* d_in, const int* in_sizes, int n_in,
                              void* d_out, int out_size, void* d_ws, size_t ws_size,
                              hipStream_t stream)
{
    const float* x  = (const float*)d_in[0];
    const int*   ei = (const int*)d_in[1];
    const float* W1 = (const float*)d_in[2];
    const float* b1 = (const float*)d_in[3];
    const float* W2 = (const float*)d_in[4];
    const float* b2 = (const float*)d_in[5];
    float* out = (float*)d_out;

    char* p = (char*)d_ws;
    float* U = (float*)p;                  p += (size_t)N_NODES * 64 * 4;
    float* V = (float*)p;                  p += (size_t)N_NODES * 64 * 4;
    __bf16* w2hi = (__bf16*)p;             p += 64 * 64 * 2;
    __bf16* w2lo = (__bf16*)p;             p += 64 * 64 * 2;
    int* counts   = (int*)p;               p += (size_t)N_NODES * 4;
    int* ovf_cnt  = (int*)p;               p += 16;
    int2* ovf     = (int2*)p;              p += (size_t)MAX_OVF * 8;
    int* buckets  = (int*)p;               p += (size_t)N_NODES * CAP * 4;

    prep_kernel<<<PREP_GRID, 256, 0, stream>>>(x, W1, b1, W2, U, V, w2hi, w2lo,
                                               counts, ovf_cnt);
    scatter_kernel<<<(N_EDGES + 255) / 256, 256, 0, stream>>>(ei, counts,
                                                              buckets, ovf, ovf_cnt);
    node_kernel<<<2048, 256, 0, stream>>>(counts, buckets, ovf, ovf_cnt,
                                          U, V, w2hi, w2lo, b2, out);
}